// Round 5
// baseline (818.153 us; speedup 1.0000x reference)
//
#include <hip/hip_runtime.h>

#define SEQ 2048
#define BB 4
#define DM 1024
#define NH 16
#define DH 64
#define ROWS (BB*SEQ)

typedef _Float16 f16;
typedef _Float16 f16x8 __attribute__((ext_vector_type(8)));
typedef _Float16 f16x4 __attribute__((ext_vector_type(4)));
typedef float f32x4 __attribute__((ext_vector_type(4)));
typedef float f32x16 __attribute__((ext_vector_type(16)));
typedef unsigned u32x4 __attribute__((ext_vector_type(4)));

__device__ __forceinline__ f32x4 mfma16(f16x8 a, f16x8 b, f32x4 c) {
    return __builtin_amdgcn_mfma_f32_16x16x32_f16(a, b, c, 0, 0, 0);
}
__device__ __forceinline__ f32x16 mfma32(f16x8 a, f16x8 b, f32x16 c) {
    return __builtin_amdgcn_mfma_f32_32x32x16_f16(a, b, c, 0, 0, 0);
}
__device__ __forceinline__ unsigned pkh(float a, float b) {
    auto h = __builtin_amdgcn_cvt_pkrtz(a, b);   // __fp16 ext_vector(2)
    return __builtin_bit_cast(unsigned, h);
}
// v_permlane32_swap_b32 (vdst=a, vsrc=b):
//   new_a = {lo: a.lo, hi: b.lo}   (a's upper half replaced by b's lower half)
//   new_b = {lo: a.hi, hi: b.hi}   (b's lower half replaced by a's upper half)
__device__ __forceinline__ void plswap(unsigned& a, unsigned& b) {
    auto r = __builtin_amdgcn_permlane32_swap((int)a, (int)b, false, false);
    a = (unsigned)r[0];
    b = (unsigned)r[1];
}
__device__ __forceinline__ float2 plswapf(float x) {
    int xi = __builtin_bit_cast(int, x);
    auto r = __builtin_amdgcn_permlane32_swap(xi, xi, false, false);
    return float2{ __builtin_bit_cast(float, (int)r[0]), __builtin_bit_cast(float, (int)r[1]) };
}

// ---------------- weight conversion fp32 -> f16 ----------------
__global__ __launch_bounds__(256) void cvt_weights(
    const float* __restrict__ wq, const float* __restrict__ wk,
    const float* __restrict__ wv, const float* __restrict__ wo,
    f16* __restrict__ oq, f16* __restrict__ ok,
    f16* __restrict__ ov, f16* __restrict__ oo) {
    int i = (blockIdx.x * 256 + threadIdx.x) * 4;
    float4 a = *(const float4*)(wq + i);
    float4 b = *(const float4*)(wk + i);
    float4 c = *(const float4*)(wv + i);
    float4 d = *(const float4*)(wo + i);
    f16x4 va = { (f16)a.x, (f16)a.y, (f16)a.z, (f16)a.w };
    f16x4 vb = { (f16)b.x, (f16)b.y, (f16)b.z, (f16)b.w };
    f16x4 vc = { (f16)c.x, (f16)c.y, (f16)c.z, (f16)c.w };
    f16x4 vd = { (f16)d.x, (f16)d.y, (f16)d.z, (f16)d.w };
    *(f16x4*)(oq + i) = va;
    *(f16x4*)(ok + i) = vb;
    *(f16x4*)(ov + i) = vc;
    *(f16x4*)(oo + i) = vd;
}

// ---------------- QKV projection GEMM ----------------
// mode 0: write [b][h][s][dh]   (q, k)
// mode 2: write [b][h][dh][s]   (v transposed)
__global__ __launch_bounds__(256) void proj_kernel(
    const float* __restrict__ X, const f16* __restrict__ W,
    const float* __restrict__ bias, f16* __restrict__ out,
    float scale, int mode) {
    const int lane = threadIdx.x & 63;
    const int wave = threadIdx.x >> 6;
    const int lo = lane & 15, hi = lane >> 4;
    const int rowbase = blockIdx.x * 64 + wave * 16;
    const int colbase = blockIdx.y * 256;

    f32x4 acc[16];
#pragma unroll
    for (int t = 0; t < 16; ++t) acc[t] = (f32x4){0.f, 0.f, 0.f, 0.f};

    const float* ap = X + (size_t)(rowbase + lo) * DM + hi * 8;
    for (int k0 = 0; k0 < DM; k0 += 32) {
        float4 a0 = *(const float4*)(ap);
        float4 a1 = *(const float4*)(ap + 4);
        ap += 32;
        f16x8 a;
        a[0] = (f16)a0.x; a[1] = (f16)a0.y; a[2] = (f16)a0.z; a[3] = (f16)a0.w;
        a[4] = (f16)a1.x; a[5] = (f16)a1.y; a[6] = (f16)a1.z; a[7] = (f16)a1.w;
        const f16* wp = W + (size_t)(colbase + lo) * DM + k0 + hi * 8;
#pragma unroll
        for (int t = 0; t < 16; ++t) {
            f16x8 b = *(const f16x8*)(wp + (size_t)t * 16 * DM);
            acc[t] = mfma16(a, b, acc[t]);
        }
    }
#pragma unroll
    for (int t = 0; t < 16; ++t) {
        int col = colbase + t * 16 + lo;
        float bv = bias[col];
        int hh = col >> 6, dh = col & 63;
#pragma unroll
        for (int r = 0; r < 4; ++r) {
            int row = rowbase + hi * 4 + r;
            int bi = row >> 11;
            int ss = row & (SEQ - 1);
            float v = (acc[t][r] + bv) * scale;
            size_t dst;
            if (mode == 2)
                dst = (((size_t)(bi * NH + hh) * DH + dh) * SEQ + ss);
            else
                dst = (((size_t)(bi * NH + hh) * SEQ + ss) * DH + dh);
            out[dst] = (f16)v;
        }
    }
}

// ---------------- fused flash attention (32x32 swapped-QK, pipelined) ----
// grid: (SEQ/32, BB*NH), block 64 (1 wave, 32 q-rows).
// Scores pre-scaled by log2(e)/sqrt(DH) (folded into q16), softmax uses exp2.
__global__ __launch_bounds__(64, 3) void attn_kernel(
    const f16* __restrict__ q16, const f16* __restrict__ k16,
    const f16* __restrict__ v16t, const int* __restrict__ mask,
    f16* __restrict__ out16) {
    const int lane = threadIdx.x & 63;
    const int lo = lane & 31;       // q-row / key row (K A-frag) / d row (V A-frag)
    const int hw = lane >> 5;       // wave half
    const int bh = blockIdx.y;
    const int b = bh >> 4, hd = bh & 15;
    const int q0 = blockIdx.x * 32;

    const f16* qp = q16 + ((size_t)bh * SEQ + q0 + lo) * DH + hw * 8;
    const f16* kp = k16 + (size_t)bh * SEQ * DH;
    const f16* vp = v16t + (size_t)bh * DH * SEQ;
    const int* mp = mask + b * SEQ;

    f16x8 qb[4];
#pragma unroll
    for (int c = 0; c < 4; ++c) qb[c] = *(const f16x8*)(qp + c * 16);

    f32x16 ctx0, ctx1;
#pragma unroll
    for (int i = 0; i < 16; ++i) { ctx0[i] = 0.f; ctx1[i] = 0.f; }
    float m = -3e38f, l = 0.f;

    const f16* kit = kp + (size_t)lo * DH + hw * 8;
    const f16* vit = vp + (size_t)lo * SEQ + hw * 8;
    const int* mit = mp + lo;

    // K tile double-buffer: kbuf[p][0..3] = first 32 keys, [4..7] = second 32
    f16x8 kbuf[2][8];
#pragma unroll
    for (int j = 0; j < 4; ++j) {
        kbuf[0][j]     = *(const f16x8*)(kit + j * 16);
        kbuf[0][4 + j] = *(const f16x8*)(kit + 32 * DH + j * 16);
    }

    for (int kb = 0; kb < SEQ; kb += 128) {
#pragma unroll
        for (int half = 0; half < 2; ++half) {
            const int KB = kb + half * 64;
            int KBN = KB + 64;
            if (KBN >= SEQ) KBN = 0;      // dummy (values unused on last tile)

            // ---- QK^T on current K regs ----
            f32x16 st0, st1;
#pragma unroll
            for (int i = 0; i < 16; ++i) { st0[i] = 0.f; st1[i] = 0.f; }
            __builtin_amdgcn_s_setprio(1);
            st0 = mfma32(kbuf[half][0], qb[0], st0);
            st0 = mfma32(kbuf[half][1], qb[1], st0);
            st0 = mfma32(kbuf[half][2], qb[2], st0);
            st0 = mfma32(kbuf[half][3], qb[3], st0);
            st1 = mfma32(kbuf[half][4], qb[0], st1);
            st1 = mfma32(kbuf[half][5], qb[1], st1);
            st1 = mfma32(kbuf[half][6], qb[2], st1);
            st1 = mfma32(kbuf[half][7], qb[3], st1);
            __builtin_amdgcn_s_setprio(0);

            // ---- issue V loads (current tile) + K loads (next tile) + mask ----
            const f16* vpt = vit + KB;
            f16x8 va0 = *(const f16x8*)(vpt);
            f16x8 va1 = *(const f16x8*)(vpt + 16);
            f16x8 va2 = *(const f16x8*)(vpt + 32);
            f16x8 va3 = *(const f16x8*)(vpt + 48);
            f16x8 va4 = *(const f16x8*)(vpt + 32 * SEQ);
            f16x8 va5 = *(const f16x8*)(vpt + 32 * SEQ + 16);
            f16x8 va6 = *(const f16x8*)(vpt + 32 * SEQ + 32);
            f16x8 va7 = *(const f16x8*)(vpt + 32 * SEQ + 48);
            const f16* kptn = kit + (size_t)KBN * DH;
#pragma unroll
            for (int j = 0; j < 4; ++j) {
                kbuf[half ^ 1][j]     = *(const f16x8*)(kptn + j * 16);
                kbuf[half ^ 1][4 + j] = *(const f16x8*)(kptn + 32 * DH + j * 16);
            }
            int mv0 = mit[KB];
            int mv1 = mit[KB + 32];

            // ---- mask (key-only, (B,1,1,S)) ----
            unsigned bm0 = (unsigned)__ballot(mv0 != 0);
            unsigned bm1 = (unsigned)__ballot(mv1 != 0);
            if (bm0 != 0xffffffffu) {
                unsigned bs = bm0 >> (hw * 4);
#pragma unroll
                for (int r = 0; r < 16; ++r)
                    if (!((bs >> ((r & 3) + 8 * (r >> 2))) & 1)) st0[r] = -1e9f;
            }
            if (bm1 != 0xffffffffu) {
                unsigned bs = bm1 >> (hw * 4);
#pragma unroll
                for (int r = 0; r < 16; ++r)
                    if (!((bs >> ((r & 3) + 8 * (r >> 2))) & 1)) st1[r] = -1e9f;
            }

            // ---- online softmax (lane-local rows; combine halves via permlane) ----
            float mx[8];
#pragma unroll
            for (int j = 0; j < 8; ++j)
                mx[j] = fmaxf(fmaxf(st0[2 * j], st0[2 * j + 1]),
                              fmaxf(st1[2 * j], st1[2 * j + 1]));
            float tm = fmaxf(fmaxf(fmaxf(mx[0], mx[1]), fmaxf(mx[2], mx[3])),
                             fmaxf(fmaxf(mx[4], mx[5]), fmaxf(mx[6], mx[7])));
            {
                float2 pp = plswapf(tm);
                tm = fmaxf(pp.x, pp.y);
            }

            if (!__all(tm <= m)) {          // defer-max: rescale only on new max
                float mn = fmaxf(m, tm);
                float sc = exp2f(m - mn);
                l *= sc;
#pragma unroll
                for (int i = 0; i < 16; ++i) { ctx0[i] *= sc; ctx1[i] *= sc; }
                m = mn;
            }
            float ts = 0.f;
#pragma unroll
            for (int i = 0; i < 16; ++i) { st0[i] = exp2f(st0[i] - m); ts += st0[i]; }
#pragma unroll
            for (int i = 0; i < 16; ++i) { st1[i] = exp2f(st1[i] - m); ts += st1[i]; }
            {
                float2 pp = plswapf(ts);
                ts = pp.x + pp.y;
            }
            l += ts;

            // ---- P -> B-fragment (pack + permlane32_swap), PV MFMAs ----
            // Want: t0 = hw ? w2(partner-lo) : w0(own);  t2 = hw ? w2(own) : w0(partner-hi)
            // plswap(a=w0, b=w2): a' = {w0.lo, w2.lo} = t0 ; b' = {w0.hi, w2.hi} = t2
            __builtin_amdgcn_s_setprio(1);
#define PV_TILE(ST, V0C0, V0C1, V1C0, V1C1)                                        \
            {                                                                      \
                unsigned w0 = pkh(ST[0], ST[1]),   w1 = pkh(ST[2], ST[3]);         \
                unsigned w2 = pkh(ST[4], ST[5]),   w3 = pkh(ST[6], ST[7]);         \
                unsigned w4 = pkh(ST[8], ST[9]),   w5 = pkh(ST[10], ST[11]);       \
                unsigned w6 = pkh(ST[12], ST[13]), w7 = pkh(ST[14], ST[15]);       \
                {                                                                  \
                    unsigned a0 = w0, b0 = w2; plswap(a0, b0);                     \
                    unsigned a1 = w1, b1 = w3; plswap(a1, b1);                     \
                    u32x4 t = { a0, a1, b0, b1 };                                  \
                    f16x8 pb = __builtin_bit_cast(f16x8, t);                       \
                    ctx0 = mfma32(V0C0, pb, ctx0);                                 \
                    ctx1 = mfma32(V1C0, pb, ctx1);                                 \
                }                                                                  \
                {                                                                  \
                    unsigned a0 = w4, b0 = w6; plswap(a0, b0);                     \
                    unsigned a1 = w5, b1 = w7; plswap(a1, b1);                     \
                    u32x4 t = { a0, a1, b0, b1 };                                  \
                    f16x8 pb = __builtin_bit_cast(f16x8, t);                       \
                    ctx0 = mfma32(V0C1, pb, ctx0);                                 \
                    ctx1 = mfma32(V1C1, pb, ctx1);                                 \
                }                                                                  \
            }
            PV_TILE(st0, va0, va1, va4, va5)
            PV_TILE(st1, va2, va3, va6, va7)
#undef PV_TILE
            __builtin_amdgcn_s_setprio(0);
        }
    }

    // ---- epilogue: divide by l, transpose via LDS, coalesced f16 stores ----
    float rl = 1.0f / l;
    __shared__ f16 tb[32][66];
#pragma unroll
    for (int u = 0; u < 8; ++u) {
        int d0 = 2 * (u & 1) + 8 * (u >> 1) + 4 * hw;
        unsigned pw0 = pkh(ctx0[2 * u] * rl, ctx0[2 * u + 1] * rl);
        unsigned pw1 = pkh(ctx1[2 * u] * rl, ctx1[2 * u + 1] * rl);
        *(unsigned*)&tb[lo][d0] = pw0;
        *(unsigned*)&tb[lo][32 + d0] = pw1;
    }
#pragma unroll
    for (int it = 0; it < 4; ++it) {
        int r = it * 8 + (lane >> 3);
        const unsigned* src = (const unsigned*)&tb[r][0];
        int cc = (lane & 7) * 4;
        u32x4 t = { src[cc], src[cc + 1], src[cc + 2], src[cc + 3] };
        f16x8 vvv = __builtin_bit_cast(f16x8, t);
        *(f16x8*)(out16 + ((size_t)(b * SEQ) + q0 + r) * DM + hd * 64 + (lane & 7) * 8) = vvv;
    }
}

// ---------------- output projection + bias + residual ----------------
__global__ __launch_bounds__(256) void oproj_kernel(
    const f16* __restrict__ ctx16, const f16* __restrict__ W,
    const float* __restrict__ bo, const float* __restrict__ Qin,
    float* __restrict__ out) {
    const int lane = threadIdx.x & 63;
    const int wave = threadIdx.x >> 6;
    const int lo = lane & 15, hi = lane >> 4;
    const int rowbase = blockIdx.x * 64 + wave * 16;
    const int colbase = blockIdx.y * 256;

    f32x4 acc[16];
#pragma unroll
    for (int t = 0; t < 16; ++t) acc[t] = (f32x4){0.f, 0.f, 0.f, 0.f};

    const f16* ap = ctx16 + (size_t)(rowbase + lo) * DM + hi * 8;
    for (int k0 = 0; k0 < DM; k0 += 32) {
        f16x8 a = *(const f16x8*)(ap);
        ap += 32;
        const f16* wp = W + (size_t)(colbase + lo) * DM + k0 + hi * 8;
#pragma unroll
        for (int t = 0; t < 16; ++t) {
            f16x8 b = *(const f16x8*)(wp + (size_t)t * 16 * DM);
            acc[t] = mfma16(a, b, acc[t]);
        }
    }
#pragma unroll
    for (int t = 0; t < 16; ++t) {
        int col = colbase + t * 16 + lo;
        float bv = bo[col];
#pragma unroll
        for (int r = 0; r < 4; ++r) {
            int row = rowbase + hi * 4 + r;
            size_t idx = (size_t)row * DM + col;
            out[idx] = acc[t][r] + bv + Qin[idx];
        }
    }
}

// ---------------- in-place LayerNorm ----------------
__global__ __launch_bounds__(256) void ln_kernel(
    float* __restrict__ x, const float* __restrict__ gamma,
    const float* __restrict__ beta) {
    const int lane = threadIdx.x & 63;
    const int wave = threadIdx.x >> 6;
    const int row = blockIdx.x * 4 + wave;
    float* rp = x + (size_t)row * DM;

    float4 v[4];
#pragma unroll
    for (int j = 0; j < 4; ++j) v[j] = ((const float4*)rp)[lane + 64 * j];

    float sum = 0.f;
#pragma unroll
    for (int j = 0; j < 4; ++j) sum += v[j].x + v[j].y + v[j].z + v[j].w;
#pragma unroll
    for (int off = 1; off < 64; off <<= 1) sum += __shfl_xor(sum, off);
    float mean = sum * (1.f / DM);

    float vs = 0.f;
#pragma unroll
    for (int j = 0; j < 4; ++j) {
        float dx = v[j].x - mean, dy = v[j].y - mean, dz = v[j].z - mean, dw = v[j].w - mean;
        vs += dx * dx + dy * dy + dz * dz + dw * dw;
    }
#pragma unroll
    for (int off = 1; off < 64; off <<= 1) vs += __shfl_xor(vs, off);
    float rstd = rsqrtf(vs * (1.f / DM) + 1e-5f);

#pragma unroll
    for (int j = 0; j < 4; ++j) {
        int idx = lane + 64 * j;
        float4 g = ((const float4*)gamma)[idx];
        float4 bt = ((const float4*)beta)[idx];
        float4 o;
        o.x = (v[j].x - mean) * rstd * g.x + bt.x;
        o.y = (v[j].y - mean) * rstd * g.y + bt.y;
        o.z = (v[j].z - mean) * rstd * g.z + bt.z;
        o.w = (v[j].w - mean) * rstd * g.w + bt.w;
        ((float4*)rp)[idx] = o;
    }
}

extern "C" void kernel_launch(void* const* d_in, const int* in_sizes, int n_in,
                              void* d_out, int out_size, void* d_ws, size_t ws_size,
                              hipStream_t stream) {
    const float* Q    = (const float*)d_in[0];
    const float* K    = (const float*)d_in[1];
    const float* V    = (const float*)d_in[2];
    const int*   mask = (const int*)d_in[3];
    const float* Wq   = (const float*)d_in[4];
    const float* bq   = (const float*)d_in[5];
    const float* Wk   = (const float*)d_in[6];
    const float* bk   = (const float*)d_in[7];
    const float* Wv   = (const float*)d_in[8];
    const float* bv   = (const float*)d_in[9];
    const float* Wo   = (const float*)d_in[10];
    const float* bo   = (const float*)d_in[11];
    const float* gamma = (const float*)d_in[12];
    const float* beta  = (const float*)d_in[13];
    float* out = (float*)d_out;

    char* ws = (char*)d_ws;
    const size_t MB = 1024 * 1024;
    f16* wq16 = (f16*)(ws + 0 * MB);
    f16* wk16 = (f16*)(ws + 2 * MB);
    f16* wv16 = (f16*)(ws + 4 * MB);
    f16* wo16 = (f16*)(ws + 6 * MB);
    f16* q16  = (f16*)(ws + 8 * MB);
    f16* k16  = (f16*)(ws + 24 * MB);
    f16* v16t = (f16*)(ws + 40 * MB);
    f16* c16  = (f16*)(ws + 56 * MB);

    cvt_weights<<<dim3(DM * DM / (256 * 4)), dim3(256), 0, stream>>>(
        Wq, Wk, Wv, Wo, wq16, wk16, wv16, wo16);

    // fold 1/sqrt(DH) * log2(e) into q so attention can use exp2
    const float qscale = 0.125f * 1.44269504f;
    proj_kernel<<<dim3(ROWS / 64, DM / 256), dim3(256), 0, stream>>>(
        Q, wq16, bq, q16, qscale, 0);
    proj_kernel<<<dim3(ROWS / 64, DM / 256), dim3(256), 0, stream>>>(
        K, wk16, bk, k16, 1.0f, 0);
    proj_kernel<<<dim3(ROWS / 64, DM / 256), dim3(256), 0, stream>>>(
        V, wv16, bv, v16t, 1.0f, 2);

    attn_kernel<<<dim3(SEQ / 32, BB * NH), dim3(64), 0, stream>>>(
        q16, k16, v16t, mask, c16);

    oproj_kernel<<<dim3(ROWS / 64, DM / 256), dim3(256), 0, stream>>>(
        c16, wo16, bo, Q, out);

    ln_kernel<<<dim3(ROWS / 4), dim3(256), 0, stream>>>(out, gamma, beta);
}

// Round 6
// 445.133 us; speedup vs baseline: 1.8380x; 1.8380x over previous
//
#include <hip/hip_runtime.h>

#define SEQ 2048
#define BB 4
#define DM 1024
#define NH 16
#define DH 64
#define ROWS (BB*SEQ)

#define BM 128
#define BN 128
#define BK 32
#define KSTEPS (DM / BK)

typedef _Float16 f16;
typedef _Float16 f16x8 __attribute__((ext_vector_type(8)));
typedef _Float16 f16x4 __attribute__((ext_vector_type(4)));
typedef float f32x4 __attribute__((ext_vector_type(4)));
typedef float f32x16 __attribute__((ext_vector_type(16)));
typedef unsigned u32x4 __attribute__((ext_vector_type(4)));

__device__ __forceinline__ f32x4 mfma16(f16x8 a, f16x8 b, f32x4 c) {
    return __builtin_amdgcn_mfma_f32_16x16x32_f16(a, b, c, 0, 0, 0);
}
__device__ __forceinline__ f32x16 mfma32(f16x8 a, f16x8 b, f32x16 c) {
    return __builtin_amdgcn_mfma_f32_32x32x16_f16(a, b, c, 0, 0, 0);
}
__device__ __forceinline__ unsigned pkh(float a, float b) {
    auto h = __builtin_amdgcn_cvt_pkrtz(a, b);   // __fp16 ext_vector(2)
    return __builtin_bit_cast(unsigned, h);
}
// v_permlane32_swap_b32 (vdst=a, vsrc=b):
//   new_a = {lo: a.lo, hi: b.lo};  new_b = {lo: a.hi, hi: b.hi}
__device__ __forceinline__ void plswap(unsigned& a, unsigned& b) {
    auto r = __builtin_amdgcn_permlane32_swap((int)a, (int)b, false, false);
    a = (unsigned)r[0];
    b = (unsigned)r[1];
}
__device__ __forceinline__ float2 plswapf(float x) {
    int xi = __builtin_bit_cast(int, x);
    auto r = __builtin_amdgcn_permlane32_swap(xi, xi, false, false);
    return float2{ __builtin_bit_cast(float, (int)r[0]), __builtin_bit_cast(float, (int)r[1]) };
}
// async global->LDS, 16B per lane; LDS dest = wave-uniform base + lane*16
typedef const __attribute__((address_space(1))) void gvoid;
typedef __attribute__((address_space(3))) void lvoid;
__device__ __forceinline__ void gload16(const f16* g, f16* l) {
    __builtin_amdgcn_global_load_lds((gvoid*)g, (lvoid*)l, 16, 0, 0);
}

// ---------------- weight conversion fp32 -> f16 ----------------
__global__ __launch_bounds__(256) void cvt_weights(
    const float* __restrict__ wq, const float* __restrict__ wk,
    const float* __restrict__ wv, const float* __restrict__ wo,
    f16* __restrict__ oq, f16* __restrict__ ok,
    f16* __restrict__ ov, f16* __restrict__ oo) {
    int i = (blockIdx.x * 256 + threadIdx.x) * 4;
    float4 a = *(const float4*)(wq + i);
    float4 b = *(const float4*)(wk + i);
    float4 c = *(const float4*)(wv + i);
    float4 d = *(const float4*)(wo + i);
    f16x4 va = { (f16)a.x, (f16)a.y, (f16)a.z, (f16)a.w };
    f16x4 vb = { (f16)b.x, (f16)b.y, (f16)b.z, (f16)b.w };
    f16x4 vc = { (f16)c.x, (f16)c.y, (f16)c.z, (f16)c.w };
    f16x4 vd = { (f16)d.x, (f16)d.y, (f16)d.z, (f16)d.w };
    *(f16x4*)(oq + i) = va;
    *(f16x4*)(ok + i) = vb;
    *(f16x4*)(ov + i) = vc;
    *(f16x4*)(oo + i) = vd;
}

// ---------------- input conversion fp32 -> f16 ----------------
__global__ __launch_bounds__(256) void cvt_x(
    const float* __restrict__ in, f16* __restrict__ out) {
    int i = (blockIdx.x * 256 + threadIdx.x) * 4;
    float4 a = *(const float4*)(in + i);
    f16x4 v = { (f16)a.x, (f16)a.y, (f16)a.z, (f16)a.w };
    *(f16x4*)(out + i) = v;
}

// ---------------- m97-style 128x128 GEMM, QKV projection ----------------
// A [M][K] f16, W [N][K] f16 (row-major, K-contig). out = (A.W^T + bias)*scale
// mode 0: write [b][h][s][dh]   (q, k);  mode 2: write [b][h][dh][s]  (v^T)
__global__ __launch_bounds__(256) void gemm_proj(
    const f16* __restrict__ A, const f16* __restrict__ W,
    const float* __restrict__ bias, f16* __restrict__ out,
    float scale, int mode) {
    __shared__ f16 lds_a[2][BM][BK];
    __shared__ f16 lds_b[2][BN][BK];
    const int lane = threadIdx.x & 63;
    const int wv = threadIdx.x >> 6;           // 0..3
    const int wr = wv >> 1, wc = wv & 1;       // 2x2 waves, 64x64 each
    const int lo = lane & 15, hi = lane >> 4;
    const int rowbase = blockIdx.x * BM;
    const int colbase = blockIdx.y * BN;

    f32x4 acc[4][4];
#pragma unroll
    for (int m = 0; m < 4; ++m)
#pragma unroll
        for (int n = 0; n < 4; ++n) acc[m][n] = (f32x4){0.f, 0.f, 0.f, 0.f};

#define STAGE_TILES(buf, k0)                                                        \
    {                                                                               \
        int r_ = lane >> 2, kc_ = (lane & 3) * 8;                                   \
        gload16(A + (size_t)(rowbase + wv * 16 + r_) * DM + (k0) + kc_,             \
                &lds_a[buf][wv * 16][0]);                                           \
        gload16(A + (size_t)(rowbase + (wv + 4) * 16 + r_) * DM + (k0) + kc_,       \
                &lds_a[buf][(wv + 4) * 16][0]);                                     \
        gload16(W + (size_t)(colbase + wv * 16 + r_) * DM + (k0) + kc_,             \
                &lds_b[buf][wv * 16][0]);                                           \
        gload16(W + (size_t)(colbase + (wv + 4) * 16 + r_) * DM + (k0) + kc_,       \
                &lds_b[buf][(wv + 4) * 16][0]);                                     \
    }

    STAGE_TILES(0, 0)
    __syncthreads();
    int buf = 0;
    for (int ks = 0; ks < KSTEPS; ++ks) {
        if (ks + 1 < KSTEPS) STAGE_TILES(buf ^ 1, (ks + 1) * BK)
        f16x8 af[4], bf[4];
#pragma unroll
        for (int m = 0; m < 4; ++m)
            af[m] = *(const f16x8*)&lds_a[buf][wr * 64 + m * 16 + lo][hi * 8];
#pragma unroll
        for (int n = 0; n < 4; ++n)
            bf[n] = *(const f16x8*)&lds_b[buf][wc * 64 + n * 16 + lo][hi * 8];
#pragma unroll
        for (int m = 0; m < 4; ++m)
#pragma unroll
            for (int n = 0; n < 4; ++n)
                acc[m][n] = mfma16(af[m], bf[n], acc[m][n]);
        __syncthreads();
        buf ^= 1;
    }
#undef STAGE_TILES

#pragma unroll
    for (int n = 0; n < 4; ++n) {
        int col = colbase + wc * 64 + n * 16 + lo;
        float bv = bias[col];
        int hh = col >> 6, dh = col & 63;
#pragma unroll
        for (int m = 0; m < 4; ++m)
#pragma unroll
            for (int r = 0; r < 4; ++r) {
                int row = rowbase + wr * 64 + m * 16 + hi * 4 + r;
                int bi = row >> 11;
                int ss = row & (SEQ - 1);
                float v = (acc[m][n][r] + bv) * scale;
                size_t dst;
                if (mode == 2)
                    dst = (((size_t)(bi * NH + hh) * DH + dh) * SEQ + ss);
                else
                    dst = (((size_t)(bi * NH + hh) * SEQ + ss) * DH + dh);
                out[dst] = (f16)v;
            }
    }
}

// ---------------- m97-style GEMM, output projection + bias + residual ----------
__global__ __launch_bounds__(256) void gemm_oproj(
    const f16* __restrict__ A, const f16* __restrict__ W,
    const float* __restrict__ bo, const float* __restrict__ Qin,
    float* __restrict__ out) {
    __shared__ f16 lds_a[2][BM][BK];
    __shared__ f16 lds_b[2][BN][BK];
    const int lane = threadIdx.x & 63;
    const int wv = threadIdx.x >> 6;
    const int wr = wv >> 1, wc = wv & 1;
    const int lo = lane & 15, hi = lane >> 4;
    const int rowbase = blockIdx.x * BM;
    const int colbase = blockIdx.y * BN;

    f32x4 acc[4][4];
#pragma unroll
    for (int m = 0; m < 4; ++m)
#pragma unroll
        for (int n = 0; n < 4; ++n) acc[m][n] = (f32x4){0.f, 0.f, 0.f, 0.f};

#define STAGE_TILES(buf, k0)                                                        \
    {                                                                               \
        int r_ = lane >> 2, kc_ = (lane & 3) * 8;                                   \
        gload16(A + (size_t)(rowbase + wv * 16 + r_) * DM + (k0) + kc_,             \
                &lds_a[buf][wv * 16][0]);                                           \
        gload16(A + (size_t)(rowbase + (wv + 4) * 16 + r_) * DM + (k0) + kc_,       \
                &lds_a[buf][(wv + 4) * 16][0]);                                     \
        gload16(W + (size_t)(colbase + wv * 16 + r_) * DM + (k0) + kc_,             \
                &lds_b[buf][wv * 16][0]);                                           \
        gload16(W + (size_t)(colbase + (wv + 4) * 16 + r_) * DM + (k0) + kc_,       \
                &lds_b[buf][(wv + 4) * 16][0]);                                     \
    }

    STAGE_TILES(0, 0)
    __syncthreads();
    int buf = 0;
    for (int ks = 0; ks < KSTEPS; ++ks) {
        if (ks + 1 < KSTEPS) STAGE_TILES(buf ^ 1, (ks + 1) * BK)
        f16x8 af[4], bf[4];
#pragma unroll
        for (int m = 0; m < 4; ++m)
            af[m] = *(const f16x8*)&lds_a[buf][wr * 64 + m * 16 + lo][hi * 8];
#pragma unroll
        for (int n = 0; n < 4; ++n)
            bf[n] = *(const f16x8*)&lds_b[buf][wc * 64 + n * 16 + lo][hi * 8];
#pragma unroll
        for (int m = 0; m < 4; ++m)
#pragma unroll
            for (int n = 0; n < 4; ++n)
                acc[m][n] = mfma16(af[m], bf[n], acc[m][n]);
        __syncthreads();
        buf ^= 1;
    }
#undef STAGE_TILES

#pragma unroll
    for (int n = 0; n < 4; ++n) {
        int col = colbase + wc * 64 + n * 16 + lo;
        float bv = bo[col];
#pragma unroll
        for (int m = 0; m < 4; ++m)
#pragma unroll
            for (int r = 0; r < 4; ++r) {
                int row = rowbase + wr * 64 + m * 16 + hi * 4 + r;
                size_t idx = (size_t)row * DM + col;
                out[idx] = acc[m][n][r] + bv + Qin[idx];
            }
    }
}

// ---------------- fused flash attention (32x32 swapped-QK, pipelined) ----
// grid: (SEQ/32, BB*NH), block 64 (1 wave, 32 q-rows).
__global__ __launch_bounds__(64, 3) void attn_kernel(
    const f16* __restrict__ q16, const f16* __restrict__ k16,
    const f16* __restrict__ v16t, const int* __restrict__ mask,
    f16* __restrict__ out16) {
    const int lane = threadIdx.x & 63;
    const int lo = lane & 31;
    const int hw = lane >> 5;
    const int bh = blockIdx.y;
    const int b = bh >> 4, hd = bh & 15;
    const int q0 = blockIdx.x * 32;

    const f16* qp = q16 + ((size_t)bh * SEQ + q0 + lo) * DH + hw * 8;
    const f16* kp = k16 + (size_t)bh * SEQ * DH;
    const f16* vp = v16t + (size_t)bh * DH * SEQ;
    const int* mp = mask + b * SEQ;

    f16x8 qb[4];
#pragma unroll
    for (int c = 0; c < 4; ++c) qb[c] = *(const f16x8*)(qp + c * 16);

    f32x16 ctx0, ctx1;
#pragma unroll
    for (int i = 0; i < 16; ++i) { ctx0[i] = 0.f; ctx1[i] = 0.f; }
    float m = -3e38f, l = 0.f;

    const f16* kit = kp + (size_t)lo * DH + hw * 8;
    const f16* vit = vp + (size_t)lo * SEQ + hw * 8;
    const int* mit = mp + lo;

    f16x8 kbuf[2][8];
#pragma unroll
    for (int j = 0; j < 4; ++j) {
        kbuf[0][j]     = *(const f16x8*)(kit + j * 16);
        kbuf[0][4 + j] = *(const f16x8*)(kit + 32 * DH + j * 16);
    }

    for (int kb = 0; kb < SEQ; kb += 128) {
#pragma unroll
        for (int half = 0; half < 2; ++half) {
            const int KB = kb + half * 64;
            int KBN = KB + 64;
            if (KBN >= SEQ) KBN = 0;

            f32x16 st0, st1;
#pragma unroll
            for (int i = 0; i < 16; ++i) { st0[i] = 0.f; st1[i] = 0.f; }
            __builtin_amdgcn_s_setprio(1);
            st0 = mfma32(kbuf[half][0], qb[0], st0);
            st0 = mfma32(kbuf[half][1], qb[1], st0);
            st0 = mfma32(kbuf[half][2], qb[2], st0);
            st0 = mfma32(kbuf[half][3], qb[3], st0);
            st1 = mfma32(kbuf[half][4], qb[0], st1);
            st1 = mfma32(kbuf[half][5], qb[1], st1);
            st1 = mfma32(kbuf[half][6], qb[2], st1);
            st1 = mfma32(kbuf[half][7], qb[3], st1);
            __builtin_amdgcn_s_setprio(0);

            const f16* vpt = vit + KB;
            f16x8 va0 = *(const f16x8*)(vpt);
            f16x8 va1 = *(const f16x8*)(vpt + 16);
            f16x8 va2 = *(const f16x8*)(vpt + 32);
            f16x8 va3 = *(const f16x8*)(vpt + 48);
            f16x8 va4 = *(const f16x8*)(vpt + 32 * SEQ);
            f16x8 va5 = *(const f16x8*)(vpt + 32 * SEQ + 16);
            f16x8 va6 = *(const f16x8*)(vpt + 32 * SEQ + 32);
            f16x8 va7 = *(const f16x8*)(vpt + 32 * SEQ + 48);
            const f16* kptn = kit + (size_t)KBN * DH;
#pragma unroll
            for (int j = 0; j < 4; ++j) {
                kbuf[half ^ 1][j]     = *(const f16x8*)(kptn + j * 16);
                kbuf[half ^ 1][4 + j] = *(const f16x8*)(kptn + 32 * DH + j * 16);
            }
            int mv0 = mit[KB];
            int mv1 = mit[KB + 32];

            unsigned bm0 = (unsigned)__ballot(mv0 != 0);
            unsigned bm1 = (unsigned)__ballot(mv1 != 0);
            if (bm0 != 0xffffffffu) {
                unsigned bs = bm0 >> (hw * 4);
#pragma unroll
                for (int r = 0; r < 16; ++r)
                    if (!((bs >> ((r & 3) + 8 * (r >> 2))) & 1)) st0[r] = -1e9f;
            }
            if (bm1 != 0xffffffffu) {
                unsigned bs = bm1 >> (hw * 4);
#pragma unroll
                for (int r = 0; r < 16; ++r)
                    if (!((bs >> ((r & 3) + 8 * (r >> 2))) & 1)) st1[r] = -1e9f;
            }

            float mx[8];
#pragma unroll
            for (int j = 0; j < 8; ++j)
                mx[j] = fmaxf(fmaxf(st0[2 * j], st0[2 * j + 1]),
                              fmaxf(st1[2 * j], st1[2 * j + 1]));
            float tm = fmaxf(fmaxf(fmaxf(mx[0], mx[1]), fmaxf(mx[2], mx[3])),
                             fmaxf(fmaxf(mx[4], mx[5]), fmaxf(mx[6], mx[7])));
            {
                float2 pp = plswapf(tm);
                tm = fmaxf(pp.x, pp.y);
            }

            if (!__all(tm <= m)) {
                float mn = fmaxf(m, tm);
                float sc = exp2f(m - mn);
                l *= sc;
#pragma unroll
                for (int i = 0; i < 16; ++i) { ctx0[i] *= sc; ctx1[i] *= sc; }
                m = mn;
            }
            float ts = 0.f;
#pragma unroll
            for (int i = 0; i < 16; ++i) { st0[i] = exp2f(st0[i] - m); ts += st0[i]; }
#pragma unroll
            for (int i = 0; i < 16; ++i) { st1[i] = exp2f(st1[i] - m); ts += st1[i]; }
            {
                float2 pp = plswapf(ts);
                ts = pp.x + pp.y;
            }
            l += ts;

            __builtin_amdgcn_s_setprio(1);
#define PV_TILE(ST, V0C0, V0C1, V1C0, V1C1)                                        \
            {                                                                      \
                unsigned w0 = pkh(ST[0], ST[1]),   w1 = pkh(ST[2], ST[3]);         \
                unsigned w2 = pkh(ST[4], ST[5]),   w3 = pkh(ST[6], ST[7]);         \
                unsigned w4 = pkh(ST[8], ST[9]),   w5 = pkh(ST[10], ST[11]);       \
                unsigned w6 = pkh(ST[12], ST[13]), w7 = pkh(ST[14], ST[15]);       \
                {                                                                  \
                    unsigned a0 = w0, b0 = w2; plswap(a0, b0);                     \
                    unsigned a1 = w1, b1 = w3; plswap(a1, b1);                     \
                    u32x4 t = { a0, a1, b0, b1 };                                  \
                    f16x8 pb = __builtin_bit_cast(f16x8, t);                       \
                    ctx0 = mfma32(V0C0, pb, ctx0);                                 \
                    ctx1 = mfma32(V1C0, pb, ctx1);                                 \
                }                                                                  \
                {                                                                  \
                    unsigned a0 = w4, b0 = w6; plswap(a0, b0);                     \
                    unsigned a1 = w5, b1 = w7; plswap(a1, b1);                     \
                    u32x4 t = { a0, a1, b0, b1 };                                  \
                    f16x8 pb = __builtin_bit_cast(f16x8, t);                       \
                    ctx0 = mfma32(V0C1, pb, ctx0);                                 \
                    ctx1 = mfma32(V1C1, pb, ctx1);                                 \
                }                                                                  \
            }
            PV_TILE(st0, va0, va1, va4, va5)
            PV_TILE(st1, va2, va3, va6, va7)
#undef PV_TILE
            __builtin_amdgcn_s_setprio(0);
        }
    }

    float rl = 1.0f / l;
    __shared__ f16 tb[32][66];
#pragma unroll
    for (int u = 0; u < 8; ++u) {
        int d0 = 2 * (u & 1) + 8 * (u >> 1) + 4 * hw;
        unsigned pw0 = pkh(ctx0[2 * u] * rl, ctx0[2 * u + 1] * rl);
        unsigned pw1 = pkh(ctx1[2 * u] * rl, ctx1[2 * u + 1] * rl);
        *(unsigned*)&tb[lo][d0] = pw0;
        *(unsigned*)&tb[lo][32 + d0] = pw1;
    }
#pragma unroll
    for (int it = 0; it < 4; ++it) {
        int r = it * 8 + (lane >> 3);
        const unsigned* src = (const unsigned*)&tb[r][0];
        int cc = (lane & 7) * 4;
        u32x4 t = { src[cc], src[cc + 1], src[cc + 2], src[cc + 3] };
        f16x8 vvv = __builtin_bit_cast(f16x8, t);
        *(f16x8*)(out16 + ((size_t)(b * SEQ) + q0 + r) * DM + hd * 64 + (lane & 7) * 8) = vvv;
    }
}

// ---------------- in-place LayerNorm ----------------
__global__ __launch_bounds__(256) void ln_kernel(
    float* __restrict__ x, const float* __restrict__ gamma,
    const float* __restrict__ beta) {
    const int lane = threadIdx.x & 63;
    const int wave = threadIdx.x >> 6;
    const int row = blockIdx.x * 4 + wave;
    float* rp = x + (size_t)row * DM;

    float4 v[4];
#pragma unroll
    for (int j = 0; j < 4; ++j) v[j] = ((const float4*)rp)[lane + 64 * j];

    float sum = 0.f;
#pragma unroll
    for (int j = 0; j < 4; ++j) sum += v[j].x + v[j].y + v[j].z + v[j].w;
#pragma unroll
    for (int off = 1; off < 64; off <<= 1) sum += __shfl_xor(sum, off);
    float mean = sum * (1.f / DM);

    float vs = 0.f;
#pragma unroll
    for (int j = 0; j < 4; ++j) {
        float dx = v[j].x - mean, dy = v[j].y - mean, dz = v[j].z - mean, dw = v[j].w - mean;
        vs += dx * dx + dy * dy + dz * dz + dw * dw;
    }
#pragma unroll
    for (int off = 1; off < 64; off <<= 1) vs += __shfl_xor(vs, off);
    float rstd = rsqrtf(vs * (1.f / DM) + 1e-5f);

#pragma unroll
    for (int j = 0; j < 4; ++j) {
        int idx = lane + 64 * j;
        float4 g = ((const float4*)gamma)[idx];
        float4 bt = ((const float4*)beta)[idx];
        float4 o;
        o.x = (v[j].x - mean) * rstd * g.x + bt.x;
        o.y = (v[j].y - mean) * rstd * g.y + bt.y;
        o.z = (v[j].z - mean) * rstd * g.z + bt.z;
        o.w = (v[j].w - mean) * rstd * g.w + bt.w;
        ((float4*)rp)[idx] = o;
    }
}

extern "C" void kernel_launch(void* const* d_in, const int* in_sizes, int n_in,
                              void* d_out, int out_size, void* d_ws, size_t ws_size,
                              hipStream_t stream) {
    const float* Q    = (const float*)d_in[0];
    const float* K    = (const float*)d_in[1];
    const float* V    = (const float*)d_in[2];
    const int*   mask = (const int*)d_in[3];
    const float* Wq   = (const float*)d_in[4];
    const float* bq   = (const float*)d_in[5];
    const float* Wk   = (const float*)d_in[6];
    const float* bk   = (const float*)d_in[7];
    const float* Wv   = (const float*)d_in[8];
    const float* bv   = (const float*)d_in[9];
    const float* Wo   = (const float*)d_in[10];
    const float* bo   = (const float*)d_in[11];
    const float* gamma = (const float*)d_in[12];
    const float* beta  = (const float*)d_in[13];
    float* out = (float*)d_out;

    char* ws = (char*)d_ws;
    const size_t MB = 1024 * 1024;
    f16* wq16 = (f16*)(ws + 0 * MB);
    f16* wk16 = (f16*)(ws + 2 * MB);
    f16* wv16 = (f16*)(ws + 4 * MB);
    f16* wo16 = (f16*)(ws + 6 * MB);
    f16* x16  = (f16*)(ws + 8 * MB);   // serially reused for Q,K,V inputs
    f16* c16  = (f16*)(ws + 8 * MB);   // alias: attn writes after proj-v reads x16
    f16* q16  = (f16*)(ws + 24 * MB);
    f16* k16  = (f16*)(ws + 40 * MB);
    f16* v16t = (f16*)(ws + 56 * MB);  // total 72 MB

    cvt_weights<<<dim3(DM * DM / (256 * 4)), dim3(256), 0, stream>>>(
        Wq, Wk, Wv, Wo, wq16, wk16, wv16, wo16);

    const dim3 ggrid(ROWS / BM, DM / BN);
    const dim3 cgrid(ROWS * DM / (256 * 4));
    const float qscale = 0.125f * 1.44269504f;   // 1/sqrt(DH) * log2(e)

    cvt_x<<<cgrid, dim3(256), 0, stream>>>(Q, x16);
    gemm_proj<<<ggrid, dim3(256), 0, stream>>>(x16, wq16, bq, q16, qscale, 0);
    cvt_x<<<cgrid, dim3(256), 0, stream>>>(K, x16);
    gemm_proj<<<ggrid, dim3(256), 0, stream>>>(x16, wk16, bk, k16, 1.0f, 0);
    cvt_x<<<cgrid, dim3(256), 0, stream>>>(V, x16);
    gemm_proj<<<ggrid, dim3(256), 0, stream>>>(x16, wv16, bv, v16t, 1.0f, 2);

    attn_kernel<<<dim3(SEQ / 32, BB * NH), dim3(64), 0, stream>>>(
        q16, k16, v16t, mask, c16);

    gemm_oproj<<<ggrid, dim3(256), 0, stream>>>(c16, wo16, bo, Q, out);

    ln_kernel<<<dim3(ROWS / 4), dim3(256), 0, stream>>>(out, gamma, beta);
}

// Round 7
// 315.044 us; speedup vs baseline: 2.5970x; 1.4129x over previous
//
#include <hip/hip_runtime.h>

#define SEQ 2048
#define BB 4
#define DM 1024
#define NH 16
#define DH 64
#define ROWS (BB*SEQ)

#define BM 128
#define BN 128
#define BK 32
#define KSTEPS (DM / BK)

#define KVBLK 64
#define NT (SEQ / KVBLK)
#define AW 4

typedef _Float16 f16;
typedef _Float16 f16x8 __attribute__((ext_vector_type(8)));
typedef _Float16 f16x4 __attribute__((ext_vector_type(4)));
typedef float f32x4 __attribute__((ext_vector_type(4)));
typedef float f32x16 __attribute__((ext_vector_type(16)));
typedef unsigned u32x4 __attribute__((ext_vector_type(4)));

__device__ __forceinline__ f32x4 mfma16(f16x8 a, f16x8 b, f32x4 c) {
    return __builtin_amdgcn_mfma_f32_16x16x32_f16(a, b, c, 0, 0, 0);
}
__device__ __forceinline__ f32x16 mfma32(f16x8 a, f16x8 b, f32x16 c) {
    return __builtin_amdgcn_mfma_f32_32x32x16_f16(a, b, c, 0, 0, 0);
}
__device__ __forceinline__ unsigned pkh(float a, float b) {
    auto h = __builtin_amdgcn_cvt_pkrtz(a, b);   // __fp16 ext_vector(2)
    return __builtin_bit_cast(unsigned, h);
}
// v_permlane32_swap_b32 (vdst=a, vsrc=b):
//   new_a = {lo: a.lo, hi: b.lo};  new_b = {lo: a.hi, hi: b.hi}
__device__ __forceinline__ void plswap(unsigned& a, unsigned& b) {
    auto r = __builtin_amdgcn_permlane32_swap((int)a, (int)b, false, false);
    a = (unsigned)r[0];
    b = (unsigned)r[1];
}
__device__ __forceinline__ float2 plswapf(float x) {
    int xi = __builtin_bit_cast(int, x);
    auto r = __builtin_amdgcn_permlane32_swap(xi, xi, false, false);
    return float2{ __builtin_bit_cast(float, (int)r[0]), __builtin_bit_cast(float, (int)r[1]) };
}
// async global->LDS, 16B per lane; LDS dest = wave-uniform base + lane*16
typedef const __attribute__((address_space(1))) void gvoid;
typedef __attribute__((address_space(3))) void lvoid;
__device__ __forceinline__ void gload16(const f16* g, f16* l) {
    __builtin_amdgcn_global_load_lds((gvoid*)g, (lvoid*)l, 16, 0, 0);
}

// ---------------- weight conversion fp32 -> f16 ----------------
__global__ __launch_bounds__(256) void cvt_weights(
    const float* __restrict__ wq, const float* __restrict__ wk,
    const float* __restrict__ wv, const float* __restrict__ wo,
    f16* __restrict__ oq, f16* __restrict__ ok,
    f16* __restrict__ ov, f16* __restrict__ oo) {
    int i = (blockIdx.x * 256 + threadIdx.x) * 4;
    float4 a = *(const float4*)(wq + i);
    float4 b = *(const float4*)(wk + i);
    float4 c = *(const float4*)(wv + i);
    float4 d = *(const float4*)(wo + i);
    f16x4 va = { (f16)a.x, (f16)a.y, (f16)a.z, (f16)a.w };
    f16x4 vb = { (f16)b.x, (f16)b.y, (f16)b.z, (f16)b.w };
    f16x4 vc = { (f16)c.x, (f16)c.y, (f16)c.z, (f16)c.w };
    f16x4 vd = { (f16)d.x, (f16)d.y, (f16)d.z, (f16)d.w };
    *(f16x4*)(oq + i) = va;
    *(f16x4*)(ok + i) = vb;
    *(f16x4*)(ov + i) = vc;
    *(f16x4*)(oo + i) = vd;
}

// ---------------- input conversion fp32 -> f16 ----------------
__global__ __launch_bounds__(256) void cvt_x(
    const float* __restrict__ in, f16* __restrict__ out) {
    int i = (blockIdx.x * 256 + threadIdx.x) * 4;
    float4 a = *(const float4*)(in + i);
    f16x4 v = { (f16)a.x, (f16)a.y, (f16)a.z, (f16)a.w };
    *(f16x4*)(out + i) = v;
}

// ---------------- m97-style 128x128 GEMM, QKV projection ----------------
// A [M][K] f16, W [N][K] f16 (row-major, K-contig). out = (A.W^T + bias)*scale
// mode 0: write [b][h][s][dh]   (q, k);  mode 2: write [b][h][dh][s]  (v^T)
__global__ __launch_bounds__(256) void gemm_proj(
    const f16* __restrict__ A, const f16* __restrict__ W,
    const float* __restrict__ bias, f16* __restrict__ out,
    float scale, int mode) {
    __shared__ f16 lds_a[2][BM][BK];
    __shared__ f16 lds_b[2][BN][BK];
    const int lane = threadIdx.x & 63;
    const int wv = threadIdx.x >> 6;
    const int wr = wv >> 1, wc = wv & 1;
    const int lo = lane & 15, hi = lane >> 4;
    const int rowbase = blockIdx.x * BM;
    const int colbase = blockIdx.y * BN;

    f32x4 acc[4][4];
#pragma unroll
    for (int m = 0; m < 4; ++m)
#pragma unroll
        for (int n = 0; n < 4; ++n) acc[m][n] = (f32x4){0.f, 0.f, 0.f, 0.f};

#define STAGE_TILES(buf, k0)                                                        \
    {                                                                               \
        int r_ = lane >> 2, kc_ = (lane & 3) * 8;                                   \
        gload16(A + (size_t)(rowbase + wv * 16 + r_) * DM + (k0) + kc_,             \
                &lds_a[buf][wv * 16][0]);                                           \
        gload16(A + (size_t)(rowbase + (wv + 4) * 16 + r_) * DM + (k0) + kc_,       \
                &lds_a[buf][(wv + 4) * 16][0]);                                     \
        gload16(W + (size_t)(colbase + wv * 16 + r_) * DM + (k0) + kc_,             \
                &lds_b[buf][wv * 16][0]);                                           \
        gload16(W + (size_t)(colbase + (wv + 4) * 16 + r_) * DM + (k0) + kc_,       \
                &lds_b[buf][(wv + 4) * 16][0]);                                     \
    }

    STAGE_TILES(0, 0)
    __syncthreads();
    int buf = 0;
    for (int ks = 0; ks < KSTEPS; ++ks) {
        if (ks + 1 < KSTEPS) STAGE_TILES(buf ^ 1, (ks + 1) * BK)
        f16x8 af[4], bf[4];
#pragma unroll
        for (int m = 0; m < 4; ++m)
            af[m] = *(const f16x8*)&lds_a[buf][wr * 64 + m * 16 + lo][hi * 8];
#pragma unroll
        for (int n = 0; n < 4; ++n)
            bf[n] = *(const f16x8*)&lds_b[buf][wc * 64 + n * 16 + lo][hi * 8];
#pragma unroll
        for (int m = 0; m < 4; ++m)
#pragma unroll
            for (int n = 0; n < 4; ++n)
                acc[m][n] = mfma16(af[m], bf[n], acc[m][n]);
        __syncthreads();
        buf ^= 1;
    }
#undef STAGE_TILES

#pragma unroll
    for (int n = 0; n < 4; ++n) {
        int col = colbase + wc * 64 + n * 16 + lo;
        float bv = bias[col];
        int hh = col >> 6, dh = col & 63;
#pragma unroll
        for (int m = 0; m < 4; ++m)
#pragma unroll
            for (int r = 0; r < 4; ++r) {
                int row = rowbase + wr * 64 + m * 16 + hi * 4 + r;
                int bi = row >> 11;
                int ss = row & (SEQ - 1);
                float v = (acc[m][n][r] + bv) * scale;
                size_t dst;
                if (mode == 2)
                    dst = (((size_t)(bi * NH + hh) * DH + dh) * SEQ + ss);
                else
                    dst = (((size_t)(bi * NH + hh) * SEQ + ss) * DH + dh);
                out[dst] = (f16)v;
            }
    }
}

// ---------------- m97-style GEMM, output projection + bias + residual ----------
__global__ __launch_bounds__(256) void gemm_oproj(
    const f16* __restrict__ A, const f16* __restrict__ W,
    const float* __restrict__ bo, const float* __restrict__ Qin,
    float* __restrict__ out) {
    __shared__ f16 lds_a[2][BM][BK];
    __shared__ f16 lds_b[2][BN][BK];
    const int lane = threadIdx.x & 63;
    const int wv = threadIdx.x >> 6;
    const int wr = wv >> 1, wc = wv & 1;
    const int lo = lane & 15, hi = lane >> 4;
    const int rowbase = blockIdx.x * BM;
    const int colbase = blockIdx.y * BN;

    f32x4 acc[4][4];
#pragma unroll
    for (int m = 0; m < 4; ++m)
#pragma unroll
        for (int n = 0; n < 4; ++n) acc[m][n] = (f32x4){0.f, 0.f, 0.f, 0.f};

#define STAGE_TILES(buf, k0)                                                        \
    {                                                                               \
        int r_ = lane >> 2, kc_ = (lane & 3) * 8;                                   \
        gload16(A + (size_t)(rowbase + wv * 16 + r_) * DM + (k0) + kc_,             \
                &lds_a[buf][wv * 16][0]);                                           \
        gload16(A + (size_t)(rowbase + (wv + 4) * 16 + r_) * DM + (k0) + kc_,       \
                &lds_a[buf][(wv + 4) * 16][0]);                                     \
        gload16(W + (size_t)(colbase + wv * 16 + r_) * DM + (k0) + kc_,             \
                &lds_b[buf][wv * 16][0]);                                           \
        gload16(W + (size_t)(colbase + (wv + 4) * 16 + r_) * DM + (k0) + kc_,       \
                &lds_b[buf][(wv + 4) * 16][0]);                                     \
    }

    STAGE_TILES(0, 0)
    __syncthreads();
    int buf = 0;
    for (int ks = 0; ks < KSTEPS; ++ks) {
        if (ks + 1 < KSTEPS) STAGE_TILES(buf ^ 1, (ks + 1) * BK)
        f16x8 af[4], bf[4];
#pragma unroll
        for (int m = 0; m < 4; ++m)
            af[m] = *(const f16x8*)&lds_a[buf][wr * 64 + m * 16 + lo][hi * 8];
#pragma unroll
        for (int n = 0; n < 4; ++n)
            bf[n] = *(const f16x8*)&lds_b[buf][wc * 64 + n * 16 + lo][hi * 8];
#pragma unroll
        for (int m = 0; m < 4; ++m)
#pragma unroll
            for (int n = 0; n < 4; ++n)
                acc[m][n] = mfma16(af[m], bf[n], acc[m][n]);
        __syncthreads();
        buf ^= 1;
    }
#undef STAGE_TILES

#pragma unroll
    for (int n = 0; n < 4; ++n) {
        int col = colbase + wc * 64 + n * 16 + lo;
        float bv = bo[col];
#pragma unroll
        for (int m = 0; m < 4; ++m)
#pragma unroll
            for (int r = 0; r < 4; ++r) {
                int row = rowbase + wr * 64 + m * 16 + hi * 4 + r;
                size_t idx = (size_t)row * DM + col;
                out[idx] = acc[m][n][r] + bv + Qin[idx];
            }
    }
}

// ---------------- fused flash attention: LDS-staged K/V, 4 waves/block ----------
// grid: (SEQ/128, BB*NH), block 256. Wave wv owns q-rows [q0, q0+32).
// K tile [64 keys][64 dh], V^T tile [64 dh][64 keys], both 8 KB, double-buffered,
// XOR-swizzled (source pre-swizzle + swizzled ds_read; 2-way conflicts = free).
__global__ __launch_bounds__(256, 2) void attn_kernel(
    const f16* __restrict__ q16, const f16* __restrict__ k16,
    const f16* __restrict__ v16t, const int* __restrict__ mask,
    f16* __restrict__ out16) {
    __shared__ f16 smem[2][2][KVBLK * 64];    // [K/V][buf][tile] = 32 KB
    const int tid = threadIdx.x;
    const int lane = tid & 63;
    const int wv = tid >> 6;
    const int lo = lane & 31, hw = lane >> 5;
    const int bh = blockIdx.y;
    const int b = bh >> 4, hd = bh & 15;
    const int q0 = blockIdx.x * (AW * 32) + wv * 32;

    const f16* qp = q16 + ((size_t)bh * SEQ + q0 + lo) * DH + hw * 8;
    const f16* kp = k16 + (size_t)bh * SEQ * DH;
    const f16* vp = v16t + (size_t)bh * DH * SEQ;
    const int* mit = mask + b * SEQ + lo;

    // staging lane mapping: 8 lanes per row, swizzled col-block
    const int sr = lane >> 3;        // row-in-group 0..7
    const int scb = lane & 7;        // linear col-block

    f16x8 qb[4];
#pragma unroll
    for (int c = 0; c < 4; ++c) qb[c] = *(const f16x8*)(qp + c * 16);

    f32x16 ctx0, ctx1;
#pragma unroll
    for (int i = 0; i < 16; ++i) { ctx0[i] = 0.f; ctx1[i] = 0.f; }
    float m = -3e38f, l = 0.f;

    // each wave stages rows [wv*16, wv*16+16) of both tiles (2 gload16 pairs)
#define STAGE(buf, KB)                                                              \
    {                                                                               \
        const int i0 = wv * 2;                                                      \
        int cb0 = scb ^ sr;                                                         \
        int cb1 = scb ^ sr ^ 2;                                                     \
        gload16(kp + (size_t)((KB) + i0 * 8 + sr) * DH + cb0 * 8,                   \
                &smem[0][buf][i0 * 512]);                                           \
        gload16(vp + (size_t)(i0 * 8 + sr) * SEQ + (KB) + cb0 * 8,                  \
                &smem[1][buf][i0 * 512]);                                           \
        gload16(kp + (size_t)((KB) + i0 * 8 + 8 + sr) * DH + cb1 * 8,               \
                &smem[0][buf][i0 * 512 + 512]);                                     \
        gload16(vp + (size_t)(i0 * 8 + 8 + sr) * SEQ + (KB) + cb1 * 8,              \
                &smem[1][buf][i0 * 512 + 512]);                                     \
    }

    STAGE(0, 0)
    __syncthreads();

    const int swz = ((lo & 7) << 3) ^ (((lo >> 3) & 1) << 4);
    int buf = 0;
    for (int t = 0; t < NT; ++t) {
        const int KB = t * KVBLK;
        if (t + 1 < NT) STAGE(buf ^ 1, KB + KVBLK)

        // ---- fragments from LDS (swizzled) ----
        f16x8 kf[2][4], vf[2][4];
#pragma unroll
        for (int kt = 0; kt < 2; ++kt)
#pragma unroll
            for (int c = 0; c < 4; ++c) {
                int idx = (((kt * 32 + lo) * 64) + (2 * c + hw) * 8) ^ swz;
                kf[kt][c] = *(const f16x8*)&smem[0][buf][idx];
                vf[kt][c] = *(const f16x8*)&smem[1][buf][idx];
            }

        // ---- QK^T ----
        f32x16 st0, st1;
#pragma unroll
        for (int i = 0; i < 16; ++i) { st0[i] = 0.f; st1[i] = 0.f; }
        __builtin_amdgcn_s_setprio(1);
        st0 = mfma32(kf[0][0], qb[0], st0);
        st0 = mfma32(kf[0][1], qb[1], st0);
        st0 = mfma32(kf[0][2], qb[2], st0);
        st0 = mfma32(kf[0][3], qb[3], st0);
        st1 = mfma32(kf[1][0], qb[0], st1);
        st1 = mfma32(kf[1][1], qb[1], st1);
        st1 = mfma32(kf[1][2], qb[2], st1);
        st1 = mfma32(kf[1][3], qb[3], st1);
        __builtin_amdgcn_s_setprio(0);

        // ---- mask (key-only, (B,1,1,S)) ----
        int mv0 = mit[KB];
        int mv1 = mit[KB + 32];
        unsigned bm0 = (unsigned)__ballot(mv0 != 0);
        unsigned bm1 = (unsigned)__ballot(mv1 != 0);
        if (bm0 != 0xffffffffu) {
            unsigned bs = bm0 >> (hw * 4);
#pragma unroll
            for (int r = 0; r < 16; ++r)
                if (!((bs >> ((r & 3) + 8 * (r >> 2))) & 1)) st0[r] = -1e9f;
        }
        if (bm1 != 0xffffffffu) {
            unsigned bs = bm1 >> (hw * 4);
#pragma unroll
            for (int r = 0; r < 16; ++r)
                if (!((bs >> ((r & 3) + 8 * (r >> 2))) & 1)) st1[r] = -1e9f;
        }

        // ---- online softmax (lane-local rows; combine halves via permlane) ----
        float mx[8];
#pragma unroll
        for (int j = 0; j < 8; ++j)
            mx[j] = fmaxf(fmaxf(st0[2 * j], st0[2 * j + 1]),
                          fmaxf(st1[2 * j], st1[2 * j + 1]));
        float tm = fmaxf(fmaxf(fmaxf(mx[0], mx[1]), fmaxf(mx[2], mx[3])),
                         fmaxf(fmaxf(mx[4], mx[5]), fmaxf(mx[6], mx[7])));
        {
            float2 pp = plswapf(tm);
            tm = fmaxf(pp.x, pp.y);
        }

        if (!__all(tm <= m)) {          // defer-max: rescale only on new max
            float mn = fmaxf(m, tm);
            float sc = exp2f(m - mn);
            l *= sc;
#pragma unroll
            for (int i = 0; i < 16; ++i) { ctx0[i] *= sc; ctx1[i] *= sc; }
            m = mn;
        }
        float ts = 0.f;
#pragma unroll
        for (int i = 0; i < 16; ++i) { st0[i] = exp2f(st0[i] - m); ts += st0[i]; }
#pragma unroll
        for (int i = 0; i < 16; ++i) { st1[i] = exp2f(st1[i] - m); ts += st1[i]; }
        {
            float2 pp = plswapf(ts);
            ts = pp.x + pp.y;
        }
        l += ts;

        // ---- P -> B-fragment (pack + permlane32_swap), PV MFMAs ----
        __builtin_amdgcn_s_setprio(1);
#define PV_TILE(ST, V0C0, V0C1, V1C0, V1C1)                                        \
        {                                                                          \
            unsigned w0 = pkh(ST[0], ST[1]),   w1 = pkh(ST[2], ST[3]);             \
            unsigned w2 = pkh(ST[4], ST[5]),   w3 = pkh(ST[6], ST[7]);             \
            unsigned w4 = pkh(ST[8], ST[9]),   w5 = pkh(ST[10], ST[11]);           \
            unsigned w6 = pkh(ST[12], ST[13]), w7 = pkh(ST[14], ST[15]);           \
            {                                                                      \
                unsigned a0 = w0, b0 = w2; plswap(a0, b0);                         \
                unsigned a1 = w1, b1 = w3; plswap(a1, b1);                         \
                u32x4 t = { a0, a1, b0, b1 };                                      \
                f16x8 pb = __builtin_bit_cast(f16x8, t);                           \
                ctx0 = mfma32(V0C0, pb, ctx0);                                     \
                ctx1 = mfma32(V1C0, pb, ctx1);                                     \
            }                                                                      \
            {                                                                      \
                unsigned a0 = w4, b0 = w6; plswap(a0, b0);                         \
                unsigned a1 = w5, b1 = w7; plswap(a1, b1);                         \
                u32x4 t = { a0, a1, b0, b1 };                                      \
                f16x8 pb = __builtin_bit_cast(f16x8, t);                           \
                ctx0 = mfma32(V0C1, pb, ctx0);                                     \
                ctx1 = mfma32(V1C1, pb, ctx1);                                     \
            }                                                                      \
        }
        PV_TILE(st0, vf[0][0], vf[0][1], vf[1][0], vf[1][1])
        PV_TILE(st1, vf[0][2], vf[0][3], vf[1][2], vf[1][3])
#undef PV_TILE
        __builtin_amdgcn_s_setprio(0);

        __syncthreads();
        buf ^= 1;
    }
#undef STAGE

    // ---- epilogue: divide by l, transpose via LDS (reuse smem), f16 stores ----
    float rl = 1.0f / l;
    f16* tbp = &smem[0][0][0] + wv * (32 * 66);
#pragma unroll
    for (int u = 0; u < 8; ++u) {
        int d0 = 2 * (u & 1) + 8 * (u >> 1) + 4 * hw;
        unsigned pw0 = pkh(ctx0[2 * u] * rl, ctx0[2 * u + 1] * rl);
        unsigned pw1 = pkh(ctx1[2 * u] * rl, ctx1[2 * u + 1] * rl);
        *(unsigned*)&tbp[lo * 66 + d0] = pw0;
        *(unsigned*)&tbp[lo * 66 + 32 + d0] = pw1;
    }
#pragma unroll
    for (int it = 0; it < 4; ++it) {
        int r = it * 8 + (lane >> 3);
        const unsigned* src = (const unsigned*)(tbp + r * 66);
        int cc = (lane & 7) * 4;
        u32x4 t = { src[cc], src[cc + 1], src[cc + 2], src[cc + 3] };
        f16x8 vvv = __builtin_bit_cast(f16x8, t);
        *(f16x8*)(out16 + ((size_t)(b * SEQ) + q0 + r) * DM + hd * 64 + (lane & 7) * 8) = vvv;
    }
}

// ---------------- in-place LayerNorm ----------------
__global__ __launch_bounds__(256) void ln_kernel(
    float* __restrict__ x, const float* __restrict__ gamma,
    const float* __restrict__ beta) {
    const int lane = threadIdx.x & 63;
    const int wave = threadIdx.x >> 6;
    const int row = blockIdx.x * 4 + wave;
    float* rp = x + (size_t)row * DM;

    float4 v[4];
#pragma unroll
    for (int j = 0; j < 4; ++j) v[j] = ((const float4*)rp)[lane + 64 * j];

    float sum = 0.f;
#pragma unroll
    for (int j = 0; j < 4; ++j) sum += v[j].x + v[j].y + v[j].z + v[j].w;
#pragma unroll
    for (int off = 1; off < 64; off <<= 1) sum += __shfl_xor(sum, off);
    float mean = sum * (1.f / DM);

    float vs = 0.f;
#pragma unroll
    for (int j = 0; j < 4; ++j) {
        float dx = v[j].x - mean, dy = v[j].y - mean, dz = v[j].z - mean, dw = v[j].w - mean;
        vs += dx * dx + dy * dy + dz * dz + dw * dw;
    }
#pragma unroll
    for (int off = 1; off < 64; off <<= 1) vs += __shfl_xor(vs, off);
    float rstd = rsqrtf(vs * (1.f / DM) + 1e-5f);

#pragma unroll
    for (int j = 0; j < 4; ++j) {
        int idx = lane + 64 * j;
        float4 g = ((const float4*)gamma)[idx];
        float4 bt = ((const float4*)beta)[idx];
        float4 o;
        o.x = (v[j].x - mean) * rstd * g.x + bt.x;
        o.y = (v[j].y - mean) * rstd * g.y + bt.y;
        o.z = (v[j].z - mean) * rstd * g.z + bt.z;
        o.w = (v[j].w - mean) * rstd * g.w + bt.w;
        ((float4*)rp)[idx] = o;
    }
}

extern "C" void kernel_launch(void* const* d_in, const int* in_sizes, int n_in,
                              void* d_out, int out_size, void* d_ws, size_t ws_size,
                              hipStream_t stream) {
    const float* Q    = (const float*)d_in[0];
    const float* K    = (const float*)d_in[1];
    const float* V    = (const float*)d_in[2];
    const int*   mask = (const int*)d_in[3];
    const float* Wq   = (const float*)d_in[4];
    const float* bq   = (const float*)d_in[5];
    const float* Wk   = (const float*)d_in[6];
    const float* bk   = (const float*)d_in[7];
    const float* Wv   = (const float*)d_in[8];
    const float* bv   = (const float*)d_in[9];
    const float* Wo   = (const float*)d_in[10];
    const float* bo   = (const float*)d_in[11];
    const float* gamma = (const float*)d_in[12];
    const float* beta  = (const float*)d_in[13];
    float* out = (float*)d_out;

    char* ws = (char*)d_ws;
    const size_t MB = 1024 * 1024;
    f16* wq16 = (f16*)(ws + 0 * MB);
    f16* wk16 = (f16*)(ws + 2 * MB);
    f16* wv16 = (f16*)(ws + 4 * MB);
    f16* wo16 = (f16*)(ws + 6 * MB);
    f16* x16  = (f16*)(ws + 8 * MB);   // serially reused for Q,K,V inputs
    f16* c16  = (f16*)(ws + 8 * MB);   // alias: attn writes after proj-v reads x16
    f16* q16  = (f16*)(ws + 24 * MB);
    f16* k16  = (f16*)(ws + 40 * MB);
    f16* v16t = (f16*)(ws + 56 * MB);  // total 72 MB

    cvt_weights<<<dim3(DM * DM / (256 * 4)), dim3(256), 0, stream>>>(
        Wq, Wk, Wv, Wo, wq16, wk16, wv16, wo16);

    const dim3 ggrid(ROWS / BM, DM / BN);
    const dim3 cgrid(ROWS * DM / (256 * 4));
    const float qscale = 0.125f * 1.44269504f;   // 1/sqrt(DH) * log2(e)

    cvt_x<<<cgrid, dim3(256), 0, stream>>>(Q, x16);
    gemm_proj<<<ggrid, dim3(256), 0, stream>>>(x16, wq16, bq, q16, qscale, 0);
    cvt_x<<<cgrid, dim3(256), 0, stream>>>(K, x16);
    gemm_proj<<<ggrid, dim3(256), 0, stream>>>(x16, wk16, bk, k16, 1.0f, 0);
    cvt_x<<<cgrid, dim3(256), 0, stream>>>(V, x16);
    gemm_proj<<<ggrid, dim3(256), 0, stream>>>(x16, wv16, bv, v16t, 1.0f, 2);

    attn_kernel<<<dim3(SEQ / (AW * 32), BB * NH), dim3(256), 0, stream>>>(
        q16, k16, v16t, mask, c16);

    gemm_oproj<<<ggrid, dim3(256), 0, stream>>>(c16, wo16, bo, Q, out);

    ln_kernel<<<dim3(ROWS / 4), dim3(256), 0, stream>>>(out, gamma, beta);
}

// Round 8
// 305.702 us; speedup vs baseline: 2.6763x; 1.0306x over previous
//
#include <hip/hip_runtime.h>

#define SEQ 2048
#define BB 4
#define DM 1024
#define NH 16
#define DH 64
#define ROWS (BB*SEQ)

#define BM 128
#define BN 128
#define BK 32
#define KSTEPS (DM / BK)

#define KVBLK 64
#define NT (SEQ / KVBLK)
#define AW 4
#define NBUF 3

typedef _Float16 f16;
typedef _Float16 f16x8 __attribute__((ext_vector_type(8)));
typedef _Float16 f16x4 __attribute__((ext_vector_type(4)));
typedef float f32x4 __attribute__((ext_vector_type(4)));
typedef float f32x16 __attribute__((ext_vector_type(16)));
typedef unsigned u32x4 __attribute__((ext_vector_type(4)));

__device__ __forceinline__ f32x4 mfma16(f16x8 a, f16x8 b, f32x4 c) {
    return __builtin_amdgcn_mfma_f32_16x16x32_f16(a, b, c, 0, 0, 0);
}
__device__ __forceinline__ f32x16 mfma32(f16x8 a, f16x8 b, f32x16 c) {
    return __builtin_amdgcn_mfma_f32_32x32x16_f16(a, b, c, 0, 0, 0);
}
__device__ __forceinline__ unsigned pkh(float a, float b) {
    auto h = __builtin_amdgcn_cvt_pkrtz(a, b);   // __fp16 ext_vector(2)
    return __builtin_bit_cast(unsigned, h);
}
// v_permlane32_swap_b32 (vdst=a, vsrc=b):
//   new_a = {lo: a.lo, hi: b.lo};  new_b = {lo: a.hi, hi: b.hi}
__device__ __forceinline__ void plswap(unsigned& a, unsigned& b) {
    auto r = __builtin_amdgcn_permlane32_swap((int)a, (int)b, false, false);
    a = (unsigned)r[0];
    b = (unsigned)r[1];
}
__device__ __forceinline__ float2 plswapf(float x) {
    int xi = __builtin_bit_cast(int, x);
    auto r = __builtin_amdgcn_permlane32_swap(xi, xi, false, false);
    return float2{ __builtin_bit_cast(float, (int)r[0]), __builtin_bit_cast(float, (int)r[1]) };
}
// async global->LDS, 16B per lane; LDS dest = wave-uniform base + lane*16
typedef const __attribute__((address_space(1))) void gvoid;
typedef __attribute__((address_space(3))) void lvoid;
__device__ __forceinline__ void gload16(const f16* g, f16* l) {
    __builtin_amdgcn_global_load_lds((gvoid*)g, (lvoid*)l, 16, 0, 0);
}

// ---------------- weight conversion fp32 -> f16 ----------------
__global__ __launch_bounds__(256) void cvt_weights(
    const float* __restrict__ wq, const float* __restrict__ wk,
    const float* __restrict__ wv, const float* __restrict__ wo,
    f16* __restrict__ oq, f16* __restrict__ ok,
    f16* __restrict__ ov, f16* __restrict__ oo) {
    int i = (blockIdx.x * 256 + threadIdx.x) * 4;
    float4 a = *(const float4*)(wq + i);
    float4 b = *(const float4*)(wk + i);
    float4 c = *(const float4*)(wv + i);
    float4 d = *(const float4*)(wo + i);
    f16x4 va = { (f16)a.x, (f16)a.y, (f16)a.z, (f16)a.w };
    f16x4 vb = { (f16)b.x, (f16)b.y, (f16)b.z, (f16)b.w };
    f16x4 vc = { (f16)c.x, (f16)c.y, (f16)c.z, (f16)c.w };
    f16x4 vd = { (f16)d.x, (f16)d.y, (f16)d.z, (f16)d.w };
    *(f16x4*)(oq + i) = va;
    *(f16x4*)(ok + i) = vb;
    *(f16x4*)(ov + i) = vc;
    *(f16x4*)(oo + i) = vd;
}

// ---------------- mask -> packed bitmask (256 u32 words) ----------------
__global__ __launch_bounds__(64) void pack_mask(
    const int* __restrict__ mask, unsigned* __restrict__ pm) {
    int tid = blockIdx.x * 64 + threadIdx.x;   // 0..255
    const int* mp = mask + (size_t)tid * 32;
    unsigned bits = 0;
#pragma unroll
    for (int j = 0; j < 32; ++j) bits |= (mp[j] != 0 ? 1u : 0u) << j;
    pm[tid] = bits;
}

// ---------------- 128x128 GEMM, QKV projection (A fp32, converted in-kernel) ----
// A [M][K] fp32, W [N][K] f16. out = (A.W^T + bias)*scale
// mode 0: write [b][h][s][dh]   (q, k);  mode 2: write [b][h][dh][s]  (v^T)
__global__ __launch_bounds__(256) void gemm_proj(
    const float* __restrict__ A, const f16* __restrict__ W,
    const float* __restrict__ bias, f16* __restrict__ out,
    float scale, int mode) {
    __shared__ f16 lds_a[2][BM][BK + 8];   // padded: 2-way-max read conflicts
    __shared__ f16 lds_b[2][BN][BK];
    const int tid = threadIdx.x;
    const int lane = tid & 63;
    const int wv = tid >> 6;
    const int wr = wv >> 1, wc = wv & 1;
    const int lo = lane & 15, hi = lane >> 4;
    const int rowbase = blockIdx.x * BM;
    const int colbase = blockIdx.y * BN;
    const int ar = tid >> 1;            // A row 0..127
    const int ac = (tid & 1) * 16;      // A col half

    f32x4 acc[4][4];
#pragma unroll
    for (int m = 0; m < 4; ++m)
#pragma unroll
        for (int n = 0; n < 4; ++n) acc[m][n] = (f32x4){0.f, 0.f, 0.f, 0.f};

    float4 av0, av1, av2, av3;
#define LOAD_A(k0)                                                                  \
    {                                                                               \
        const float* ap_ = A + (size_t)(rowbase + ar) * DM + (k0) + ac;             \
        av0 = *(const float4*)(ap_);                                                \
        av1 = *(const float4*)(ap_ + 4);                                            \
        av2 = *(const float4*)(ap_ + 8);                                            \
        av3 = *(const float4*)(ap_ + 12);                                           \
    }
#define WRITE_A(buf)                                                                \
    {                                                                               \
        f16* dp_ = &lds_a[buf][ar][ac];                                             \
        u32x4 t0_ = { pkh(av0.x, av0.y), pkh(av0.z, av0.w),                         \
                      pkh(av1.x, av1.y), pkh(av1.z, av1.w) };                       \
        u32x4 t1_ = { pkh(av2.x, av2.y), pkh(av2.z, av2.w),                         \
                      pkh(av3.x, av3.y), pkh(av3.z, av3.w) };                       \
        *(u32x4*)(dp_) = t0_;                                                       \
        *(u32x4*)(dp_ + 8) = t1_;                                                   \
    }
#define STAGE_W(buf, k0)                                                            \
    {                                                                               \
        int r_ = lane >> 2, kc_ = (lane & 3) * 8;                                   \
        gload16(W + (size_t)(colbase + wv * 16 + r_) * DM + (k0) + kc_,             \
                &lds_b[buf][wv * 16][0]);                                           \
        gload16(W + (size_t)(colbase + (wv + 4) * 16 + r_) * DM + (k0) + kc_,       \
                &lds_b[buf][(wv + 4) * 16][0]);                                     \
    }

    LOAD_A(0)
    STAGE_W(0, 0)
    WRITE_A(0)
    __syncthreads();
    int buf = 0;
    for (int ks = 0; ks < KSTEPS; ++ks) {
        if (ks + 1 < KSTEPS) {
            LOAD_A((ks + 1) * BK)
            STAGE_W(buf ^ 1, (ks + 1) * BK)
        }
        f16x8 af[4], bf[4];
#pragma unroll
        for (int m = 0; m < 4; ++m)
            af[m] = *(const f16x8*)&lds_a[buf][wr * 64 + m * 16 + lo][hi * 8];
#pragma unroll
        for (int n = 0; n < 4; ++n)
            bf[n] = *(const f16x8*)&lds_b[buf][wc * 64 + n * 16 + lo][hi * 8];
#pragma unroll
        for (int m = 0; m < 4; ++m)
#pragma unroll
            for (int n = 0; n < 4; ++n)
                acc[m][n] = mfma16(af[m], bf[n], acc[m][n]);
        if (ks + 1 < KSTEPS) WRITE_A(buf ^ 1)     // vm-wait lands after MFMAs
        __syncthreads();
        buf ^= 1;
    }
#undef LOAD_A
#undef WRITE_A
#undef STAGE_W

#pragma unroll
    for (int n = 0; n < 4; ++n) {
        int col = colbase + wc * 64 + n * 16 + lo;
        float bv = bias[col];
        int hh = col >> 6, dh = col & 63;
#pragma unroll
        for (int m = 0; m < 4; ++m)
#pragma unroll
            for (int r = 0; r < 4; ++r) {
                int row = rowbase + wr * 64 + m * 16 + hi * 4 + r;
                int bi = row >> 11;
                int ss = row & (SEQ - 1);
                float v = (acc[m][n][r] + bv) * scale;
                size_t dst;
                if (mode == 2)
                    dst = (((size_t)(bi * NH + hh) * DH + dh) * SEQ + ss);
                else
                    dst = (((size_t)(bi * NH + hh) * SEQ + ss) * DH + dh);
                out[dst] = (f16)v;
            }
    }
}

// ---------------- m97-style GEMM, output projection + bias + residual ----------
__global__ __launch_bounds__(256) void gemm_oproj(
    const f16* __restrict__ A, const f16* __restrict__ W,
    const float* __restrict__ bo, const float* __restrict__ Qin,
    float* __restrict__ out) {
    __shared__ f16 lds_a[2][BM][BK];
    __shared__ f16 lds_b[2][BN][BK];
    const int lane = threadIdx.x & 63;
    const int wv = threadIdx.x >> 6;
    const int wr = wv >> 1, wc = wv & 1;
    const int lo = lane & 15, hi = lane >> 4;
    const int rowbase = blockIdx.x * BM;
    const int colbase = blockIdx.y * BN;

    f32x4 acc[4][4];
#pragma unroll
    for (int m = 0; m < 4; ++m)
#pragma unroll
        for (int n = 0; n < 4; ++n) acc[m][n] = (f32x4){0.f, 0.f, 0.f, 0.f};

#define STAGE_TILES(buf, k0)                                                        \
    {                                                                               \
        int r_ = lane >> 2, kc_ = (lane & 3) * 8;                                   \
        gload16(A + (size_t)(rowbase + wv * 16 + r_) * DM + (k0) + kc_,             \
                &lds_a[buf][wv * 16][0]);                                           \
        gload16(A + (size_t)(rowbase + (wv + 4) * 16 + r_) * DM + (k0) + kc_,       \
                &lds_a[buf][(wv + 4) * 16][0]);                                     \
        gload16(W + (size_t)(colbase + wv * 16 + r_) * DM + (k0) + kc_,             \
                &lds_b[buf][wv * 16][0]);                                           \
        gload16(W + (size_t)(colbase + (wv + 4) * 16 + r_) * DM + (k0) + kc_,       \
                &lds_b[buf][(wv + 4) * 16][0]);                                     \
    }

    STAGE_TILES(0, 0)
    __syncthreads();
    int buf = 0;
    for (int ks = 0; ks < KSTEPS; ++ks) {
        if (ks + 1 < KSTEPS) STAGE_TILES(buf ^ 1, (ks + 1) * BK)
        f16x8 af[4], bf[4];
#pragma unroll
        for (int m = 0; m < 4; ++m)
            af[m] = *(const f16x8*)&lds_a[buf][wr * 64 + m * 16 + lo][hi * 8];
#pragma unroll
        for (int n = 0; n < 4; ++n)
            bf[n] = *(const f16x8*)&lds_b[buf][wc * 64 + n * 16 + lo][hi * 8];
#pragma unroll
        for (int m = 0; m < 4; ++m)
#pragma unroll
            for (int n = 0; n < 4; ++n)
                acc[m][n] = mfma16(af[m], bf[n], acc[m][n]);
        __syncthreads();
        buf ^= 1;
    }
#undef STAGE_TILES

#pragma unroll
    for (int n = 0; n < 4; ++n) {
        int col = colbase + wc * 64 + n * 16 + lo;
        float bv = bo[col];
#pragma unroll
        for (int m = 0; m < 4; ++m)
#pragma unroll
            for (int r = 0; r < 4; ++r) {
                int row = rowbase + wr * 64 + m * 16 + hi * 4 + r;
                size_t idx = (size_t)row * DM + col;
                out[idx] = acc[m][n][r] + bv + Qin[idx];
            }
    }
}

// ---------------- fused flash attention: 3-buffer counted-vmcnt pipeline --------
// grid: (SEQ/128, BB*NH), block 256 (4 waves x 32 q-rows).
__global__ __launch_bounds__(256, 2) void attn_kernel(
    const f16* __restrict__ q16, const f16* __restrict__ k16,
    const f16* __restrict__ v16t, const unsigned* __restrict__ pm,
    f16* __restrict__ out16) {
    __shared__ f16 smem[NBUF][2][KVBLK * 64];    // 48 KB
    const int tid = threadIdx.x;
    const int lane = tid & 63;
    const int wv = tid >> 6;
    const int lo = lane & 31, hw = lane >> 5;
    const int bh = blockIdx.y;
    const int b = bh >> 4, hd = bh & 15;
    const int q0 = blockIdx.x * (AW * 32) + wv * 32;

    const f16* qp = q16 + ((size_t)bh * SEQ + q0 + lo) * DH + hw * 8;
    const f16* kp = k16 + (size_t)bh * SEQ * DH;
    const f16* vp = v16t + (size_t)bh * DH * SEQ;
    const unsigned* pmb = pm + b * 64;

    const int sr = lane >> 3;        // staging row-in-group
    const int scb = lane & 7;        // staging col-block

    f16x8 qb[4];
#pragma unroll
    for (int c = 0; c < 4; ++c) qb[c] = *(const f16x8*)(qp + c * 16);

    f32x16 fz;
#pragma unroll
    for (int i = 0; i < 16; ++i) fz[i] = 0.f;
    f32x16 ctx0 = fz, ctx1 = fz, lacc = fz;
    float m = -3e38f;
    f16x8 ones8;
#pragma unroll
    for (int i = 0; i < 8; ++i) ones8[i] = (f16)1.0f;

#define STAGE(buf, KB)                                                              \
    {                                                                               \
        const int i0 = wv * 2;                                                      \
        int cb0 = scb ^ sr;                                                         \
        int cb1 = scb ^ sr ^ 2;                                                     \
        gload16(kp + (size_t)((KB) + i0 * 8 + sr) * DH + cb0 * 8,                   \
                &smem[buf][0][i0 * 512]);                                           \
        gload16(vp + (size_t)(i0 * 8 + sr) * SEQ + (KB) + cb0 * 8,                  \
                &smem[buf][1][i0 * 512]);                                           \
        gload16(kp + (size_t)((KB) + i0 * 8 + 8 + sr) * DH + cb1 * 8,               \
                &smem[buf][0][i0 * 512 + 512]);                                     \
        gload16(vp + (size_t)(i0 * 8 + 8 + sr) * SEQ + (KB) + cb1 * 8,              \
                &smem[buf][1][i0 * 512 + 512]);                                     \
    }

    STAGE(0, 0)
    STAGE(1, KVBLK)

    const int swz = ((lo & 7) << 3) ^ (((lo >> 3) & 1) << 4);
    int bc = 0;                       // t % 3
    for (int t = 0; t < NT; ++t) {
        // counted wait: own STAGE(t) landed (4 newest = STAGE(t+1) may fly)
        if (t + 2 < NT) asm volatile("s_waitcnt vmcnt(4)" ::: "memory");
        else            asm volatile("s_waitcnt vmcnt(0)" ::: "memory");
        __builtin_amdgcn_s_barrier();
        asm volatile("" ::: "memory");

        // ---- fragments from LDS (swizzled) ----
        f16x8 kf[2][4], vf[2][4];
#pragma unroll
        for (int kt = 0; kt < 2; ++kt)
#pragma unroll
            for (int c = 0; c < 4; ++c) {
                int idx = (((kt * 32 + lo) * 64) + (2 * c + hw) * 8) ^ swz;
                kf[kt][c] = *(const f16x8*)&smem[bc][0][idx];
                vf[kt][c] = *(const f16x8*)&smem[bc][1][idx];
            }

        // ---- prefetch 2 tiles ahead ----
        if (t + 2 < NT) {
            int bs = bc + 2; if (bs >= NBUF) bs -= NBUF;
            STAGE(bs, (t + 2) * KVBLK)
        }

        // ---- QK^T (zero-register C: no acc-init movs) ----
        f32x16 st0, st1;
        __builtin_amdgcn_s_setprio(1);
        st0 = mfma32(kf[0][0], qb[0], fz);
        st0 = mfma32(kf[0][1], qb[1], st0);
        st0 = mfma32(kf[0][2], qb[2], st0);
        st0 = mfma32(kf[0][3], qb[3], st0);
        st1 = mfma32(kf[1][0], qb[0], fz);
        st1 = mfma32(kf[1][1], qb[1], st1);
        st1 = mfma32(kf[1][2], qb[2], st1);
        st1 = mfma32(kf[1][3], qb[3], st1);
        __builtin_amdgcn_s_setprio(0);

        // ---- mask (packed bits, scalar loads -> lgkm, keeps vmcnt clean) ----
        unsigned bm0 = pmb[2 * t];
        unsigned bm1 = pmb[2 * t + 1];
        if (bm0 != 0xffffffffu) {
            unsigned bs_ = bm0 >> (hw * 4);
#pragma unroll
            for (int r = 0; r < 16; ++r)
                if (!((bs_ >> ((r & 3) + 8 * (r >> 2))) & 1)) st0[r] = -1e9f;
        }
        if (bm1 != 0xffffffffu) {
            unsigned bs_ = bm1 >> (hw * 4);
#pragma unroll
            for (int r = 0; r < 16; ++r)
                if (!((bs_ >> ((r & 3) + 8 * (r >> 2))) & 1)) st1[r] = -1e9f;
        }

        // ---- online softmax max (max3-fusable chains) ----
        float tma = fmaxf(st0[0], st0[1]);
#pragma unroll
        for (int i = 2; i < 16; i += 2) tma = fmaxf(fmaxf(tma, st0[i]), st0[i + 1]);
        float tmb = fmaxf(st1[0], st1[1]);
#pragma unroll
        for (int i = 2; i < 16; i += 2) tmb = fmaxf(fmaxf(tmb, st1[i]), st1[i + 1]);
        float tm = fmaxf(tma, tmb);
        {
            float2 pp = plswapf(tm);
            tm = fmaxf(pp.x, pp.y);
        }

        if (!__all(tm <= m)) {          // defer-max: rescale only on new max
            float mn = fmaxf(m, tm);
            float sc = exp2f(m - mn);
#pragma unroll
            for (int i = 0; i < 16; ++i) { ctx0[i] *= sc; ctx1[i] *= sc; }
            lacc[0] *= sc;
            m = mn;
        }
#pragma unroll
        for (int i = 0; i < 16; ++i) st0[i] = exp2f(st0[i] - m);
#pragma unroll
        for (int i = 0; i < 16; ++i) st1[i] = exp2f(st1[i] - m);

        // ---- P -> B-fragment, PV MFMAs, l via ones-MFMA ----
        __builtin_amdgcn_s_setprio(1);
#define PV_TILE(ST, V0C0, V0C1, V1C0, V1C1)                                        \
        {                                                                          \
            unsigned w0 = pkh(ST[0], ST[1]),   w1 = pkh(ST[2], ST[3]);             \
            unsigned w2 = pkh(ST[4], ST[5]),   w3 = pkh(ST[6], ST[7]);             \
            unsigned w4 = pkh(ST[8], ST[9]),   w5 = pkh(ST[10], ST[11]);           \
            unsigned w6 = pkh(ST[12], ST[13]), w7 = pkh(ST[14], ST[15]);           \
            {                                                                      \
                unsigned a0 = w0, b0 = w2; plswap(a0, b0);                         \
                unsigned a1 = w1, b1 = w3; plswap(a1, b1);                         \
                u32x4 t_ = { a0, a1, b0, b1 };                                     \
                f16x8 pb = __builtin_bit_cast(f16x8, t_);                          \
                ctx0 = mfma32(V0C0, pb, ctx0);                                     \
                ctx1 = mfma32(V1C0, pb, ctx1);                                     \
                lacc = mfma32(ones8, pb, lacc);                                    \
            }                                                                      \
            {                                                                      \
                unsigned a0 = w4, b0 = w6; plswap(a0, b0);                         \
                unsigned a1 = w5, b1 = w7; plswap(a1, b1);                         \
                u32x4 t_ = { a0, a1, b0, b1 };                                     \
                f16x8 pb = __builtin_bit_cast(f16x8, t_);                          \
                ctx0 = mfma32(V0C1, pb, ctx0);                                     \
                ctx1 = mfma32(V1C1, pb, ctx1);                                     \
                lacc = mfma32(ones8, pb, lacc);                                    \
            }                                                                      \
        }
        PV_TILE(st0, vf[0][0], vf[0][1], vf[1][0], vf[1][1])
        PV_TILE(st1, vf[0][2], vf[0][3], vf[1][2], vf[1][3])
#undef PV_TILE
        __builtin_amdgcn_s_setprio(0);

        bc = (bc + 1 == NBUF) ? 0 : bc + 1;
    }
#undef STAGE

    __syncthreads();   // all waves done with smem tiles before transpose reuse

    // ---- epilogue: divide by l, transpose via LDS (reuse smem), f16 stores ----
    float rl = 1.0f / lacc[0];
    f16* tbp = &smem[0][0][0] + wv * (32 * 66);
#pragma unroll
    for (int u = 0; u < 8; ++u) {
        int d0 = 2 * (u & 1) + 8 * (u >> 1) + 4 * hw;
        unsigned pw0 = pkh(ctx0[2 * u] * rl, ctx0[2 * u + 1] * rl);
        unsigned pw1 = pkh(ctx1[2 * u] * rl, ctx1[2 * u + 1] * rl);
        *(unsigned*)&tbp[lo * 66 + d0] = pw0;
        *(unsigned*)&tbp[lo * 66 + 32 + d0] = pw1;
    }
    __syncthreads();
#pragma unroll
    for (int it = 0; it < 4; ++it) {
        int r = it * 8 + (lane >> 3);
        const unsigned* src = (const unsigned*)(tbp + r * 66);
        int cc = (lane & 7) * 4;
        u32x4 t = { src[cc], src[cc + 1], src[cc + 2], src[cc + 3] };
        f16x8 vvv = __builtin_bit_cast(f16x8, t);
        *(f16x8*)(out16 + ((size_t)(b * SEQ) + q0 + r) * DM + hd * 64 + (lane & 7) * 8) = vvv;
    }
}

// ---------------- in-place LayerNorm ----------------
__global__ __launch_bounds__(256) void ln_kernel(
    float* __restrict__ x, const float* __restrict__ gamma,
    const float* __restrict__ beta) {
    const int lane = threadIdx.x & 63;
    const int wave = threadIdx.x >> 6;
    const int row = blockIdx.x * 4 + wave;
    float* rp = x + (size_t)row * DM;

    float4 v[4];
#pragma unroll
    for (int j = 0; j < 4; ++j) v[j] = ((const float4*)rp)[lane + 64 * j];

    float sum = 0.f;
#pragma unroll
    for (int j = 0; j < 4; ++j) sum += v[j].x + v[j].y + v[j].z + v[j].w;
#pragma unroll
    for (int off = 1; off < 64; off <<= 1) sum += __shfl_xor(sum, off);
    float mean = sum * (1.f / DM);

    float vs = 0.f;
#pragma unroll
    for (int j = 0; j < 4; ++j) {
        float dx = v[j].x - mean, dy = v[j].y - mean, dz = v[j].z - mean, dw = v[j].w - mean;
        vs += dx * dx + dy * dy + dz * dz + dw * dw;
    }
#pragma unroll
    for (int off = 1; off < 64; off <<= 1) vs += __shfl_xor(vs, off);
    float rstd = rsqrtf(vs * (1.f / DM) + 1e-5f);

#pragma unroll
    for (int j = 0; j < 4; ++j) {
        int idx = lane + 64 * j;
        float4 g = ((const float4*)gamma)[idx];
        float4 bt = ((const float4*)beta)[idx];
        float4 o;
        o.x = (v[j].x - mean) * rstd * g.x + bt.x;
        o.y = (v[j].y - mean) * rstd * g.y + bt.y;
        o.z = (v[j].z - mean) * rstd * g.z + bt.z;
        o.w = (v[j].w - mean) * rstd * g.w + bt.w;
        ((float4*)rp)[idx] = o;
    }
}

extern "C" void kernel_launch(void* const* d_in, const int* in_sizes, int n_in,
                              void* d_out, int out_size, void* d_ws, size_t ws_size,
                              hipStream_t stream) {
    const float* Q    = (const float*)d_in[0];
    const float* K    = (const float*)d_in[1];
    const float* V    = (const float*)d_in[2];
    const int*   mask = (const int*)d_in[3];
    const float* Wq   = (const float*)d_in[4];
    const float* bq   = (const float*)d_in[5];
    const float* Wk   = (const float*)d_in[6];
    const float* bk   = (const float*)d_in[7];
    const float* Wv   = (const float*)d_in[8];
    const float* bv   = (const float*)d_in[9];
    const float* Wo   = (const float*)d_in[10];
    const float* bo   = (const float*)d_in[11];
    const float* gamma = (const float*)d_in[12];
    const float* beta  = (const float*)d_in[13];
    float* out = (float*)d_out;

    char* ws = (char*)d_ws;
    const size_t MB = 1024 * 1024;
    f16* wq16 = (f16*)(ws + 0 * MB);
    f16* wk16 = (f16*)(ws + 2 * MB);
    f16* wv16 = (f16*)(ws + 4 * MB);
    f16* wo16 = (f16*)(ws + 6 * MB);
    f16* c16  = (f16*)(ws + 8 * MB);
    f16* q16  = (f16*)(ws + 24 * MB);
    f16* k16  = (f16*)(ws + 40 * MB);
    f16* v16t = (f16*)(ws + 56 * MB);  // total 72 MB

    // packed mask lives in the tail of d_out; oproj overwrites all of out later
    unsigned* pm = (unsigned*)((char*)d_out + (size_t)out_size * 4 - 4096);

    cvt_weights<<<dim3(DM * DM / (256 * 4)), dim3(256), 0, stream>>>(
        Wq, Wk, Wv, Wo, wq16, wk16, wv16, wo16);
    pack_mask<<<dim3(4), dim3(64), 0, stream>>>(mask, pm);

    const dim3 ggrid(ROWS / BM, DM / BN);
    const float qscale = 0.125f * 1.44269504f;   // 1/sqrt(DH) * log2(e)

    gemm_proj<<<ggrid, dim3(256), 0, stream>>>(Q, wq16, bq, q16, qscale, 0);
    gemm_proj<<<ggrid, dim3(256), 0, stream>>>(K, wk16, bk, k16, 1.0f, 0);
    gemm_proj<<<ggrid, dim3(256), 0, stream>>>(V, wv16, bv, v16t, 1.0f, 2);

    attn_kernel<<<dim3(SEQ / (AW * 32), BB * NH), dim3(256), 0, stream>>>(
        q16, k16, v16t, pm, c16);

    gemm_oproj<<<ggrid, dim3(256), 0, stream>>>(c16, wo16, bo, Q, out);

    ln_kernel<<<dim3(ROWS / 4), dim3(256), 0, stream>>>(out, gamma, beta);
}